// Round 15
// baseline (119.954 us; speedup 1.0000x reference)
//
#include <hip/hip_runtime.h>
#include <hip/hip_bf16.h>
#include <cstddef>

#define S_   1024
#define HC_  1024
#define C_   64
#define LOG2E 1.4426950408889634f
#define SC2   0.18033688011112042f   /* (1/8)*log2(e) */

typedef __attribute__((ext_vector_type(8))) short bf16x8;
typedef __attribute__((ext_vector_type(4))) short bf16x4;
typedef __attribute__((ext_vector_type(4))) float f32x4;

typedef __attribute__((address_space(1))) const void gconst_t;
typedef __attribute__((address_space(3))) void lds_t;

__device__ __forceinline__ short cvt_bf16(float f) {
  union { float f; unsigned u; } v; v.f = f;
  unsigned r = v.u + 0x7FFFu + ((v.u >> 16) & 1u);
  return (short)(r >> 16);
}
__device__ __forceinline__ float bf2f(short s) {
  union { float f; unsigned u; } v; v.u = ((unsigned)(unsigned short)s) << 16;
  return v.f;
}

template<int N> __device__ __forceinline__ void wait_vm() {
  if constexpr (N == 0)       asm volatile("s_waitcnt vmcnt(0)" ::: "memory");
  else if constexpr (N == 2)  asm volatile("s_waitcnt vmcnt(2)" ::: "memory");
  else if constexpr (N == 4)  asm volatile("s_waitcnt vmcnt(4)" ::: "memory");
  else if constexpr (N == 6)  asm volatile("s_waitcnt vmcnt(6)" ::: "memory");
  else if constexpr (N == 8)  asm volatile("s_waitcnt vmcnt(8)" ::: "memory");
  else if constexpr (N == 12) asm volatile("s_waitcnt vmcnt(12)" ::: "memory");
}

// ---------------------------------------------------------------------------
// prep: weight transpose+cvt (blocks 0..5119), input cvt (5120..8191),
// bias pre-permute w/ inline mask-stride detect (8192..10239).
// ---------------------------------------------------------------------------
__global__ __launch_bounds__(256) void prep(
    const float* __restrict__ QT, const float* __restrict__ KT,
    const float* __restrict__ VT, const float* __restrict__ GW,
    const float* __restrict__ OW, short* __restrict__ WTb,
    const float* __restrict__ Qin, const float* __restrict__ Kin,
    const float* __restrict__ Vin, short* __restrict__ Abf,
    const float* __restrict__ att, const unsigned char* __restrict__ sm,
    short* __restrict__ biasP) {
  __shared__ short tile[32][33];
  __shared__ int a1, a4;
  const int bid = blockIdx.x;
  const int t = threadIdx.x;

  if (bid < 5120) {
    const int which = bid >> 10, xb = bid & 1023;
    const float* src = (which == 0) ? QT : (which == 1) ? KT : (which == 2) ? VT
                      : (which == 3) ? GW : OW;
    short* dst = WTb + (size_t)which * (1024u * 1024u);
    const int tj = (xb & 31) * 32;
    const int tk = (xb >> 5) * 32;
    const int r = t >> 3, c4 = (t & 7) * 4;
    const float4 v = *(const float4*)(src + (size_t)(tk + r) * 1024 + tj + c4);
    tile[c4 + 0][r] = cvt_bf16(v.x);
    tile[c4 + 1][r] = cvt_bf16(v.y);
    tile[c4 + 2][r] = cvt_bf16(v.z);
    tile[c4 + 3][r] = cvt_bf16(v.w);
    __syncthreads();
    bf16x4 o;
    o[0] = tile[r][c4 + 0]; o[1] = tile[r][c4 + 1];
    o[2] = tile[r][c4 + 2]; o[3] = tile[r][c4 + 3];
    *(bf16x4*)(dst + (size_t)(tj + r) * 1024 + tk + c4) = o;
  } else if (bid < 8192) {
    const int idx = bid - 5120;
    const int y = idx >> 10, xb = idx & 1023;
    const float* src = (y == 0) ? Qin : (y == 1) ? Kin : Vin;
    short* d = Abf + (size_t)y * 2097152u;
    const int i = (xb * 256 + t) * 8;
    const float4 a = *(const float4*)(src + i);
    const float4 b = *(const float4*)(src + i + 4);
    bf16x8 o;
    o[0] = cvt_bf16(a.x); o[1] = cvt_bf16(a.y); o[2] = cvt_bf16(a.z); o[3] = cvt_bf16(a.w);
    o[4] = cvt_bf16(b.x); o[5] = cvt_bf16(b.y); o[6] = cvt_bf16(b.z); o[7] = cvt_bf16(b.w);
    *(bf16x8*)(d + i) = o;
  } else {
    if (t == 0) { a1 = 0; a4 = 0; }
    __syncthreads();
    int l1 = 0, l4 = 0;
    for (int i = t; i < 2048; i += 256) {
      if (sm[i]) { if (i & 3) l1 = 1; else if (i & 4) l4 = 1; }
    }
    if (l1) atomicOr(&a1, 1);
    if (l4) atomicOr(&a4, 1);
    __syncthreads();
    const int mst = a1 ? 1 : (a4 ? 4 : 8);

    const int idx = bid - 8192;
    const int qw = idx & 63, tt = (idx >> 6) & 15, n = idx >> 10;
    const int lslot = t >> 2, i4 = t & 3;
    const int tc = tt * 64 + i4 * 16 + (lslot & 15);
    const int qbase = qw * 16 + ((lslot >> 4) << 2);
    const int smt = sm[(size_t)(n * 1024 + tc) * mst];
    bf16x4 o;
#pragma unroll
    for (int ii = 0; ii < 4; ii++) {
      const int q = qbase + ii;
      const int smq = sm[(size_t)(n * 1024 + q) * mst];
      const float val = (smq && smt) ? -1e4f : att[(size_t)q * 1024 + tc] * LOG2E;
      o[ii] = cvt_bf16(val);
    }
    short* dst = biasP + (((size_t)(n * 64 + qw) * 16 + tt) * 64 + lslot) * 16 + i4 * 4;
    *(bf16x4*)dst = o;
  }
}

// ---------------------------------------------------------------------------
// bf16 GEMM core v6 (R14, unchanged): PD=3 counted-vmcnt, 4 LDS buffers,
// one barrier per K-step, 2-way chunk swizzle both sides (0 conflicts).
// ---------------------------------------------------------------------------
template<int MW, int NW>
__device__ __forceinline__ void gemm_core_bf(
    const short* __restrict__ A, const short* __restrict__ BT,
    short* As, short* Bs, int m0, int n0, f32x4 acc[MW][NW]) {
  const int t = threadIdx.x;
  const int lane = t & 63, wid = t >> 6;
  const int wr = wid >> 1, wc = wid & 1;
  const int l15 = lane & 15, g = lane >> 4;
  constexpr int NT = 32;
  constexpr int LDT = MW / 2 + NW / 2;
  constexpr int ABUF = MW * 1024;
  constexpr int BBUF = NW * 1024;

#pragma unroll
  for (int m = 0; m < MW; m++)
#pragma unroll
    for (int n2 = 0; n2 < NW; n2++) acc[m][n2] = (f32x4){0.f, 0.f, 0.f, 0.f};

#define STAGE_(buf, kt)                                                        \
  {                                                                            \
    const int k0_ = (kt) * 32;                                                 \
    _Pragma("unroll")                                                          \
    for (int i_ = 0; i_ < NW / 2; i_++) {                                      \
      const int seg_ = i_ * 256 + t;                                           \
      const int row_ = seg_ >> 2, gl_ = seg_ & 3;                              \
      __builtin_amdgcn_global_load_lds(                                        \
          (gconst_t*)(BT + (size_t)(n0 + row_) * 1024 + k0_ +                  \
                      ((gl_ ^ ((row_ >> 1) & 3)) * 8)),                        \
          (lds_t*)(Bs + (buf) * BBUF + seg_ * 8), 16, 0, 0);                   \
    }                                                                          \
    _Pragma("unroll")                                                          \
    for (int i_ = 0; i_ < MW / 2; i_++) {                                      \
      const int seg_ = i_ * 256 + t;                                           \
      const int row_ = seg_ >> 2, gl_ = seg_ & 3;                              \
      __builtin_amdgcn_global_load_lds(                                        \
          (gconst_t*)(A + (size_t)(m0 + row_) * 1024 + k0_ +                   \
                      ((gl_ ^ ((row_ >> 1) & 3)) * 8)),                        \
          (lds_t*)(As + (buf) * ABUF + seg_ * 8), 16, 0, 0);                   \
    }                                                                          \
  }

  STAGE_(0, 0);
  STAGE_(1, 1);
  STAGE_(2, 2);
  int b0 = 0, b1 = 1, b2 = 2, b3 = 3;
  for (int kt = 0; kt < NT; ++kt) {
    if (kt + 2 < NT) {
      wait_vm<2 * LDT>();
    } else if (kt + 2 == NT) {
      wait_vm<LDT>();
    } else {
      wait_vm<0>();
    }
    __builtin_amdgcn_sched_barrier(0);
    __builtin_amdgcn_s_barrier();
    __builtin_amdgcn_sched_barrier(0);
    if (kt + 3 < NT) STAGE_(b3, kt + 3);

    const short* Ac = As + b0 * ABUF;
    const short* Bc = Bs + b0 * BBUF;
    bf16x8 a[MW], b[NW];
#pragma unroll
    for (int m = 0; m < MW; m++) {
      const int row = wr * (MW * 16) + m * 16 + l15;
      a[m] = *(const bf16x8*)(Ac + row * 32 + ((g ^ ((row >> 1) & 3)) * 8));
    }
#pragma unroll
    for (int n2 = 0; n2 < NW; n2++) {
      const int row = wc * (NW * 16) + n2 * 16 + l15;
      b[n2] = *(const bf16x8*)(Bc + row * 32 + ((g ^ ((row >> 1) & 3)) * 8));
    }
#pragma unroll
    for (int m = 0; m < MW; m++)
#pragma unroll
      for (int n2 = 0; n2 < NW; n2++)
        acc[m][n2] = __builtin_amdgcn_mfma_f32_16x16x32_bf16(a[m], b[n2], acc[m][n2], 0, 0, 0);
    const int tmp = b0; b0 = b1; b1 = b2; b2 = b3; b3 = tmp;
  }
#undef STAGE_
}

// Projections: 128x128 tiles, 1D grid 512, XCD-chunked. y==2 (V) writes its
// tile TRANSPOSED to VpT via an in-LDS transpose epilogue.
__global__ __launch_bounds__(256) void gemm_proj(
    const short* __restrict__ Abf, const short* __restrict__ WTb,
    short* __restrict__ Pb, short* __restrict__ VpT,
    const float* __restrict__ gb) {
  __shared__ short As[4 * 4096];
  __shared__ short Bs[4 * 4096];
  const int bid = blockIdx.x;
  const int xcd = bid & 7, ord = bid >> 3;
  const int y = xcd >> 1, nh = xcd & 1;
  const int m0 = (ord & 15) * 128;
  const int n0 = (nh * 4 + (ord >> 4)) * 128;
  const short* A = Abf + (size_t)((y <= 2) ? y : 2) * 2097152u;
  const short* BT = WTb + (size_t)y * (1024u * 1024u);
  f32x4 acc[4][4];
  gemm_core_bf<4, 4>(A, BT, As, Bs, m0, n0, acc);
  const int t = threadIdx.x, lane = t & 63, wid = t >> 6;
  const int wr = wid >> 1, wc = wid & 1, l15 = lane & 15, g = lane >> 4;

  if (y == 2) {
    short* Tr = As;
    __syncthreads();
#pragma unroll
    for (int m = 0; m < 4; m++)
#pragma unroll
      for (int n2 = 0; n2 < 4; n2++)
#pragma unroll
        for (int j = 0; j < 4; j++) {
          const int r = wr * 64 + m * 16 + g * 4 + j;
          const int c = wc * 64 + n2 * 16 + l15;
          Tr[c * 128 + r] = cvt_bf16(acc[m][n2][j]);
        }
    __syncthreads();
    const int nz = (m0 >= 1024) ? 1 : 0;
    const int sbase = m0 & 1023;
#pragma unroll
    for (int p = 0; p < 8; p++) {
      const int unit = p * 256 + t;
      const int cl = unit >> 4, sr8 = unit & 15;
      const bf16x8 v = *(const bf16x8*)(Tr + cl * 128 + sr8 * 8);
      *(bf16x8*)(VpT + ((size_t)(nz * 1024 + n0 + cl)) * 1024 + sbase + sr8 * 8) = v;
    }
  } else {
    short* outp = Pb + (size_t)y * 2097152u;
#pragma unroll
    for (int m = 0; m < 4; m++)
#pragma unroll
      for (int n2 = 0; n2 < 4; n2++)
#pragma unroll
        for (int j = 0; j < 4; j++) {
          const int row = m0 + wr * 64 + m * 16 + g * 4 + j;
          const int col = n0 + wc * 64 + n2 * 16 + l15;
          float v = acc[m][n2][j];
          if (y == 3) { v += gb[col]; v = 1.0f / (1.0f + __expf(-v)); }
          outp[(size_t)row * 1024 + col] = cvt_bf16(v);
        }
  }
}

// ---------------------------------------------------------------------------
// Fused merge + final projection: 64x64 tiles, 1D grid 512, XCD-chunked.
// Block rows m0..m0+63 = one (n, qb). A-subtile [64][32] for K-step kt lives
// in head h=kt>>1, half hf=kt&1: built on the fly from Opart partials with
// precomputed wscf[h][row][sp] = exp2(m_sp - M)/l, multiplied by gate, cvt
// to bf16, ds_written with the reader-congruent chunk swizzle. 2-phase dbuf.
// ---------------------------------------------------------------------------
__global__ __launch_bounds__(256) void gemm_final(
    const short* __restrict__ OpartB, const float* __restrict__ mlbuf,
    const short* __restrict__ Gp, const short* __restrict__ WTo,
    float* __restrict__ outp, const float* __restrict__ ob, int lns) {
  __shared__ short As[2 * 2048];
  __shared__ short Bs[2 * 2048];
  __shared__ float wscf[16][64][2];
  const int bid = blockIdx.x;
  const int xcd = bid & 7, ord = bid >> 3;
  const int mg = xcd >> 1, ng = xcd & 1;
  const int m0 = (mg * 8 + (ord & 7)) * 64;
  const int n0 = (ng * 8 + (ord >> 3)) * 64;
  const int t = threadIdx.x;
  const int lane = t & 63, wid = t >> 6;
  const int wr = wid >> 1, wc = wid & 1;
  const int l15 = lane & 15, g = lane >> 4;
  const int nsplit = 1 << lns;
  const int nn = m0 >> 10, s0 = m0 & 1023, qb = (m0 >> 6) & 15;

  // ---- precompute per-(head,row) merge weights
  for (int u = t; u < 16 * 64; u += 256) {
    const int h = u >> 6, row = u & 63;
    const int bslot = ((nn * 16 + h) * 16 + qb) << lns;
    const float* mlb = mlbuf + (size_t)bslot * 128 + row * 2;
    float M = -1e30f;
    for (int sp = 0; sp < nsplit; sp++) M = fmaxf(M, mlb[(size_t)sp * 128]);
    float l = 0.f;
    for (int sp = 0; sp < nsplit; sp++)
      l += exp2f(mlb[(size_t)sp * 128] - M) * mlb[(size_t)sp * 128 + 1];
    const float inv = 1.0f / l;
    wscf[h][row][0] = exp2f(mlb[0] - M) * inv;
    wscf[h][row][1] = (nsplit > 1) ? exp2f(mlb[128] - M) * inv : 0.f;
  }
  __syncthreads();

  const int arow = t >> 2, ac8 = (t & 3) * 8;   // A-build coords
  const int brow = t >> 2, bgl = t & 3;         // B-stage coords

#define BUILD_A_(buf, kt)                                                      \
  {                                                                            \
    const int h_ = (kt) >> 1, hf_ = (kt) & 1;                                  \
    const int slotb_ = ((nn * 16 + h_) * 16 + qb) << lns;                      \
    const short* p0_ = OpartB + (size_t)slotb_ * 4096 + arow * 64 + hf_ * 32 + ac8; \
    const bf16x8 q0_ = *(const bf16x8*)p0_;                                    \
    const bf16x8 q1_ = (nsplit > 1) ? *(const bf16x8*)(p0_ + 4096) : q0_;      \
    const float w0_ = wscf[h_][arow][0];                                       \
    const float w1_ = wscf[h_][arow][1];                                       \
    const bf16x8 gt_ = *(const bf16x8*)(Gp + ((size_t)(nn * 1024 + s0 + arow)) * 1024 + h_ * 64 + hf_ * 32 + ac8); \
    bf16x8 o_;                                                                 \
    _Pragma("unroll")                                                          \
    for (int j_ = 0; j_ < 8; j_++) {                                           \
      const float a_ = (w0_ * bf2f(q0_[j_]) + w1_ * bf2f(q1_[j_])) * bf2f(gt_[j_]); \
      o_[j_] = cvt_bf16(a_);                                                   \
    }                                                                          \
    *(bf16x8*)(As + (buf) * 2048 + arow * 32 + (((ac8 >> 3) ^ ((arow >> 1) & 3)) * 8)) = o_; \
  }

#define STAGE_B_(buf, kt)                                                      \
  {                                                                            \
    const int k0_ = (kt) * 32;                                                 \
    __builtin_amdgcn_global_load_lds(                                          \
        (gconst_t*)(WTo + (size_t)(n0 + brow) * 1024 + k0_ +                   \
                    ((bgl ^ ((brow >> 1) & 3)) * 8)),                          \
        (lds_t*)(Bs + (buf) * 2048 + t * 8), 16, 0, 0);                        \
  }

  f32x4 acc[2][2];
#pragma unroll
  for (int m = 0; m < 2; m++)
#pragma unroll
    for (int n2 = 0; n2 < 2; n2++) acc[m][n2] = (f32x4){0.f, 0.f, 0.f, 0.f};

  STAGE_B_(0, 0);
  BUILD_A_(0, 0);
  __syncthreads();

  for (int kt = 0; kt < 32; ++kt) {
    const int pb = kt & 1;
    const short* Ac = As + pb * 2048;
    const short* Bc = Bs + pb * 2048;
    bf16x8 a[2], b[2];
#pragma unroll
    for (int m = 0; m < 2; m++) {
      const int row = wr * 32 + m * 16 + l15;
      a[m] = *(const bf16x8*)(Ac + row * 32 + ((g ^ ((row >> 1) & 3)) * 8));
    }
#pragma unroll
    for (int n2 = 0; n2 < 2; n2++) {
      const int row = wc * 32 + n2 * 16 + l15;
      b[n2] = *(const bf16x8*)(Bc + row * 32 + ((g ^ ((row >> 1) & 3)) * 8));
    }
    if (kt + 1 < 32) {
      STAGE_B_(pb ^ 1, kt + 1);
      BUILD_A_(pb ^ 1, kt + 1);
    }
#pragma unroll
    for (int m = 0; m < 2; m++)
#pragma unroll
      for (int n2 = 0; n2 < 2; n2++)
        acc[m][n2] = __builtin_amdgcn_mfma_f32_16x16x32_bf16(a[m], b[n2], acc[m][n2], 0, 0, 0);
    __syncthreads();   // drains vm (B stage) + lgkm (A writes); orders buffers
  }
#undef BUILD_A_
#undef STAGE_B_

#pragma unroll
  for (int m = 0; m < 2; m++)
#pragma unroll
    for (int n2 = 0; n2 < 2; n2++)
#pragma unroll
      for (int j = 0; j < 4; j++) {
        const int row = m0 + wr * 32 + m * 16 + g * 4 + j;
        const int col = n0 + wc * 32 + n2 * 16 + l15;
        outp[(size_t)row * 1024 + col] = acc[m][n2][j] + ob[col];
      }
}

// ---------------------------------------------------------------------------
// Flash attention KV-split (unchanged; lns=1).
// ---------------------------------------------------------------------------
__global__ __launch_bounds__(256) void attn_split(
    const short* __restrict__ Qp, const short* __restrict__ Kp,
    const short* __restrict__ VpT, const short* __restrict__ biasP,
    float* __restrict__ mlbuf, short* __restrict__ OpartB, int lns) {
  __shared__ short Ks[64 * 64];
  __shared__ short Vt[64 * 64];
  __shared__ short Pl[4][16 * 64];

  const int t = threadIdx.x;
  const int lane = t & 63, w = t >> 6;
  const int l15 = lane & 15, g = lane >> 4;
  const int xb = blockIdx.x, h = blockIdx.y, n = blockIdx.z;
  const int sp = xb & ((1 << lns) - 1), qb = xb >> lns;
  const int itc = 16 >> lns;

  const int sbase = qb * 64 + w * 16;
  const short* qptr = Qp + (size_t)(n * S_ + sbase + l15) * HC_ + h * C_;
  const bf16x8 qf0 = *(const bf16x8*)(qptr + g * 8);
  const bf16x8 qf1 = *(const bf16x8*)(qptr + 32 + g * 8);

  float mrow[4], lsum[4];
  f32x4 oacc[4];
#pragma unroll
  for (int j = 0; j < 4; j++) { mrow[j] = -1e30f; lsum[j] = 0.f; }
#pragma unroll
  for (int cb = 0; cb < 4; cb++) oacc[cb] = (f32x4){0.f, 0.f, 0.f, 0.f};

  const int str = t >> 3, sc8 = (t & 7) * 8;
  const short* bbase = biasP + ((size_t)(n * 64 + qb * 4 + w) * 16 * 64 + lane) * 16;

  {
    const int t0 = sp * itc * 64;
    bf16x8 kA0 = *(const bf16x8*)(Kp + (size_t)(n * S_ + t0 + str) * HC_ + h * C_ + sc8);
    bf16x8 kA1 = *(const bf16x8*)(Kp + (size_t)(n * S_ + t0 + 32 + str) * HC_ + h * C_ + sc8);
    bf16x8 vA0 = *(const bf16x8*)(VpT + ((size_t)n * HC_ + h * C_ + str) * S_ + t0 + sc8);
    bf16x8 vA1 = *(const bf16x8*)(VpT + ((size_t)n * HC_ + h * C_ + 32 + str) * S_ + t0 + sc8);

    for (int it = 0; it < itc; ++it) {
      const int tg = sp * itc + it;
      __syncthreads();
      { const int kr = str;      *(bf16x8*)((char*)Ks + kr * 128 + ((sc8 * 2) ^ ((kr & 7) << 4))) = kA0; }
      { const int kr = 32 + str; *(bf16x8*)((char*)Ks + kr * 128 + ((sc8 * 2) ^ ((kr & 7) << 4))) = kA1; }
      { const int cr = str;      *(bf16x8*)((char*)Vt + cr * 128 + ((sc8 * 2) ^ ((cr & 7) << 4))) = vA0; }
      { const int cr = 32 + str; *(bf16x8*)((char*)Vt + cr * 128 + ((sc8 * 2) ^ ((cr & 7) << 4))) = vA1; }
      __syncthreads();

      const bf16x8 bf0 = *(const bf16x8*)(bbase + tg * 1024);
      const bf16x8 bf1 = *(const bf16x8*)(bbase + tg * 1024 + 8);
      const int t1 = ((it + 1 < itc) ? (tg + 1) : tg) * 64;
      bf16x8 kB0 = *(const bf16x8*)(Kp + (size_t)(n * S_ + t1 + str) * HC_ + h * C_ + sc8);
      bf16x8 kB1 = *(const bf16x8*)(Kp + (size_t)(n * S_ + t1 + 32 + str) * HC_ + h * C_ + sc8);
      bf16x8 vB0 = *(const bf16x8*)(VpT + ((size_t)n * HC_ + h * C_ + str) * S_ + t1 + sc8);
      bf16x8 vB1 = *(const bf16x8*)(VpT + ((size_t)n * HC_ + h * C_ + 32 + str) * S_ + t1 + sc8);

      f32x4 sacc[4];
#pragma unroll
      for (int nb = 0; nb < 4; nb++) sacc[nb] = (f32x4){0.f, 0.f, 0.f, 0.f};
      __builtin_amdgcn_s_setprio(1);
#pragma unroll
      for (int nb = 0; nb < 4; nb++) {
        const int krow = nb * 16 + l15;
        const bf16x8 b0 = *(const bf16x8*)((char*)Ks + krow * 128 + ((g * 16) ^ ((krow & 7) << 4)));
        const bf16x8 b1 = *(const bf16x8*)((char*)Ks + krow * 128 + ((64 + g * 16) ^ ((krow & 7) << 4)));
        sacc[nb] = __builtin_amdgcn_mfma_f32_16x16x32_bf16(qf0, b0, sacc[nb], 0, 0, 0);
        sacc[nb] = __builtin_amdgcn_mfma_f32_16x16x32_bf16(qf1, b1, sacc[nb], 0, 0, 0);
      }
      __builtin_amdgcn_s_setprio(0);

      float tmax[4];
#pragma unroll
      for (int j = 0; j < 4; j++) tmax[j] = -1e30f;
#pragma unroll
      for (int nb = 0; nb < 4; nb++)
#pragma unroll
        for (int j = 0; j < 4; j++) {
          const short bb = (nb < 2) ? bf0[nb * 4 + j] : bf1[(nb - 2) * 4 + j];
          const float lg = sacc[nb][j] * SC2 + bf2f(bb);
          sacc[nb][j] = lg;
          tmax[j] = fmaxf(tmax[j], lg);
        }
#pragma unroll
      for (int j = 0; j < 4; j++) {
#pragma unroll
        for (int d = 1; d < 16; d <<= 1)
          tmax[j] = fmaxf(tmax[j], __shfl_xor(tmax[j], d, 64));
        const float mn = fmaxf(mrow[j], tmax[j]);
        const float sc = exp2f(mrow[j] - mn);
        mrow[j] = mn;
        lsum[j] *= sc;
#pragma unroll
        for (int cb = 0; cb < 4; cb++) oacc[cb][j] *= sc;
        float ps = 0.f;
#pragma unroll
        for (int nb = 0; nb < 4; nb++) {
          const float p = exp2f(sacc[nb][j] - mn);
          sacc[nb][j] = p;
          ps += p;
        }
        lsum[j] += ps;
      }
      short* Pw = &Pl[w][0];
#pragma unroll
      for (int nb = 0; nb < 4; nb++)
#pragma unroll
        for (int j = 0; j < 4; j++) {
          const int pr = g * 4 + j;
          const int pcb = (nb * 16 + l15) * 2;
          *(short*)((char*)Pw + pr * 128 + (pcb ^ ((pr & 7) << 4))) = cvt_bf16(sacc[nb][j]);
        }
      __builtin_amdgcn_s_setprio(1);
#pragma unroll
      for (int kk = 0; kk < 2; kk++) {
        const bf16x8 pf = *(const bf16x8*)((char*)Pw + l15 * 128 + ((kk * 64 + g * 16) ^ ((l15 & 7) << 4)));
#pragma unroll
        for (int cb = 0; cb < 4; cb++) {
          const int vrow = cb * 16 + l15;
          const bf16x8 vf = *(const bf16x8*)((char*)Vt + vrow * 128 + ((kk * 64 + g * 16) ^ ((vrow & 7) << 4)));
          oacc[cb] = __builtin_amdgcn_mfma_f32_16x16x32_bf16(pf, vf, oacc[cb], 0, 0, 0);
        }
      }
      __builtin_amdgcn_s_setprio(0);
      kA0 = kB0; kA1 = kB1; vA0 = vB0; vA1 = vB1;
    }
  }
  const int slot = (((n * 16 + h) * 16 + qb) << lns) + sp;
  short* op = OpartB + (size_t)slot * 4096;
  float* mlp = mlbuf + (size_t)slot * 128;
#pragma unroll
  for (int j = 0; j < 4; j++) {
    float rs = lsum[j];
#pragma unroll
    for (int d = 1; d < 16; d <<= 1) rs += __shfl_xor(rs, d, 64);
    const int row = w * 16 + g * 4 + j;
#pragma unroll
    for (int cb = 0; cb < 4; cb++)
      op[row * 64 + cb * 16 + l15] = cvt_bf16(oacc[cb][j]);
    if (l15 == 0) { mlp[row * 2] = mrow[j]; mlp[row * 2 + 1] = rs; }
  }
}

// ---------------------------------------------------------------------------
extern "C" void kernel_launch(void* const* d_in, const int* in_sizes, int n_in,
                              void* d_out, int out_size, void* d_ws, size_t ws_size,
                              hipStream_t stream) {
  const float* Qin      = (const float*)d_in[0];
  const float* Kin      = (const float*)d_in[1];
  const float* Vin      = (const float*)d_in[2];
  const void*  seqMask  = d_in[3];
  const float* attMask  = (const float*)d_in[4];
  const float* QTrans   = (const float*)d_in[5];
  const float* KTrans   = (const float*)d_in[6];
  const float* VTrans   = (const float*)d_in[7];
  const float* GTrans_w = (const float*)d_in[8];
  const float* GTrans_b = (const float*)d_in[9];
  const float* out_w    = (const float*)d_in[10];
  const float* out_b    = (const float*)d_in[11];
  float* out = (float*)d_out;

  char* ws = (char*)d_ws;
  const size_t MB = 1048576u;
  short* WTb   = (short*)(ws);              // 10 MB: 5 transposed bf16 weights
  short* Abf   = (short*)(ws + 10 * MB);    // 12 MB: bf16 Qin,Kin,Vin
  short* Pb    = (short*)(ws + 22 * MB);    // 16 MB: Qp,Kp,(unused),Gp bf16
  short* VpT   = (short*)(ws + 38 * MB);    //  4 MB (written by gemm_proj y=2)
  short* biasP = (short*)(ws + 46 * MB);    //  4 MB pre-permuted bias
  const size_t partBase = 51 * MB;

  const short* Kp = Pb + (size_t)1u * 2097152u;
  const short* Gp = Pb + (size_t)3u * 2097152u;

  int lns = 0;
  for (int c = 1; c >= 0; c--) {
    const size_t slots = 512u << c;
    if (ws_size >= partBase + slots * (8192u + 512u)) { lns = c; break; }
  }
  const size_t slots = 512u << lns;
  short* OpartB = (short*)(ws + partBase);
  float* mlbuf  = (float*)(ws + partBase + slots * 8192u);

  hipLaunchKernelGGL(prep, dim3(10240), dim3(256), 0, stream,
                     QTrans, KTrans, VTrans, GTrans_w, out_w, WTb,
                     Qin, Kin, Vin, Abf,
                     attMask, (const unsigned char*)seqMask, biasP);
  hipLaunchKernelGGL(gemm_proj, dim3(512), dim3(256), 0, stream,
                     Abf, WTb, Pb, VpT, GTrans_b);
  hipLaunchKernelGGL(attn_split, dim3(16 << lns, 16, 2), dim3(256), 0, stream,
                     Pb, Kp, VpT, biasP, mlbuf, OpartB, lns);
  hipLaunchKernelGGL(gemm_final, dim3(512), dim3(256), 0, stream,
                     OpartB, mlbuf, Gp, WTb + (size_t)4u * 1048576u,
                     out, out_b, lns);
}

// Round 17
// 112.196 us; speedup vs baseline: 1.0691x; 1.0691x over previous
//
#include <hip/hip_runtime.h>
#include <hip/hip_bf16.h>
#include <cstddef>

#define S_   1024
#define HC_  1024
#define C_   64
#define LOG2E 1.4426950408889634f
#define SC2   0.18033688011112042f   /* (1/8)*log2(e) */

typedef __attribute__((ext_vector_type(8))) short bf16x8;
typedef __attribute__((ext_vector_type(4))) short bf16x4;
typedef __attribute__((ext_vector_type(4))) float f32x4;

typedef __attribute__((address_space(1))) const void gconst_t;
typedef __attribute__((address_space(3))) void lds_t;

__device__ __forceinline__ short cvt_bf16(float f) {
  union { float f; unsigned u; } v; v.f = f;
  unsigned r = v.u + 0x7FFFu + ((v.u >> 16) & 1u);
  return (short)(r >> 16);
}
__device__ __forceinline__ float bf2f(short s) {
  union { float f; unsigned u; } v; v.u = ((unsigned)(unsigned short)s) << 16;
  return v.f;
}

template<int N> __device__ __forceinline__ void wait_vm() {
  if constexpr (N == 0)       asm volatile("s_waitcnt vmcnt(0)" ::: "memory");
  else if constexpr (N == 2)  asm volatile("s_waitcnt vmcnt(2)" ::: "memory");
  else if constexpr (N == 4)  asm volatile("s_waitcnt vmcnt(4)" ::: "memory");
  else if constexpr (N == 6)  asm volatile("s_waitcnt vmcnt(6)" ::: "memory");
  else if constexpr (N == 8)  asm volatile("s_waitcnt vmcnt(8)" ::: "memory");
  else if constexpr (N == 12) asm volatile("s_waitcnt vmcnt(12)" ::: "memory");
}

// ---------------------------------------------------------------------------
// prep: weight transpose+cvt (blocks 0..5119), input cvt (5120..8191),
// bias pre-permute w/ inline mask-stride detect (8192..10239).
// ---------------------------------------------------------------------------
__global__ __launch_bounds__(256) void prep(
    const float* __restrict__ QT, const float* __restrict__ KT,
    const float* __restrict__ VT, const float* __restrict__ GW,
    const float* __restrict__ OW, short* __restrict__ WTb,
    const float* __restrict__ Qin, const float* __restrict__ Kin,
    const float* __restrict__ Vin, short* __restrict__ Abf,
    const float* __restrict__ att, const unsigned char* __restrict__ sm,
    short* __restrict__ biasP) {
  __shared__ short tile[32][33];
  __shared__ int a1, a4;
  const int bid = blockIdx.x;
  const int t = threadIdx.x;

  if (bid < 5120) {
    const int which = bid >> 10, xb = bid & 1023;
    const float* src = (which == 0) ? QT : (which == 1) ? KT : (which == 2) ? VT
                      : (which == 3) ? GW : OW;
    short* dst = WTb + (size_t)which * (1024u * 1024u);
    const int tj = (xb & 31) * 32;
    const int tk = (xb >> 5) * 32;
    const int r = t >> 3, c4 = (t & 7) * 4;
    const float4 v = *(const float4*)(src + (size_t)(tk + r) * 1024 + tj + c4);
    tile[c4 + 0][r] = cvt_bf16(v.x);
    tile[c4 + 1][r] = cvt_bf16(v.y);
    tile[c4 + 2][r] = cvt_bf16(v.z);
    tile[c4 + 3][r] = cvt_bf16(v.w);
    __syncthreads();
    bf16x4 o;
    o[0] = tile[r][c4 + 0]; o[1] = tile[r][c4 + 1];
    o[2] = tile[r][c4 + 2]; o[3] = tile[r][c4 + 3];
    *(bf16x4*)(dst + (size_t)(tj + r) * 1024 + tk + c4) = o;
  } else if (bid < 8192) {
    const int idx = bid - 5120;
    const int y = idx >> 10, xb = idx & 1023;
    const float* src = (y == 0) ? Qin : (y == 1) ? Kin : Vin;
    short* d = Abf + (size_t)y * 2097152u;
    const int i = (xb * 256 + t) * 8;
    const float4 a = *(const float4*)(src + i);
    const float4 b = *(const float4*)(src + i + 4);
    bf16x8 o;
    o[0] = cvt_bf16(a.x); o[1] = cvt_bf16(a.y); o[2] = cvt_bf16(a.z); o[3] = cvt_bf16(a.w);
    o[4] = cvt_bf16(b.x); o[5] = cvt_bf16(b.y); o[6] = cvt_bf16(b.z); o[7] = cvt_bf16(b.w);
    *(bf16x8*)(d + i) = o;
  } else {
    if (t == 0) { a1 = 0; a4 = 0; }
    __syncthreads();
    int l1 = 0, l4 = 0;
    for (int i = t; i < 2048; i += 256) {
      if (sm[i]) { if (i & 3) l1 = 1; else if (i & 4) l4 = 1; }
    }
    if (l1) atomicOr(&a1, 1);
    if (l4) atomicOr(&a4, 1);
    __syncthreads();
    const int mst = a1 ? 1 : (a4 ? 4 : 8);

    const int idx = bid - 8192;
    const int qw = idx & 63, tt = (idx >> 6) & 15, n = idx >> 10;
    const int lslot = t >> 2, i4 = t & 3;
    const int tc = tt * 64 + i4 * 16 + (lslot & 15);
    const int qbase = qw * 16 + ((lslot >> 4) << 2);
    const int smt = sm[(size_t)(n * 1024 + tc) * mst];
    bf16x4 o;
#pragma unroll
    for (int ii = 0; ii < 4; ii++) {
      const int q = qbase + ii;
      const int smq = sm[(size_t)(n * 1024 + q) * mst];
      const float val = (smq && smt) ? -1e4f : att[(size_t)q * 1024 + tc] * LOG2E;
      o[ii] = cvt_bf16(val);
    }
    short* dst = biasP + (((size_t)(n * 64 + qw) * 16 + tt) * 64 + lslot) * 16 + i4 * 4;
    *(bf16x4*)dst = o;
  }
}

// ---------------------------------------------------------------------------
// bf16 GEMM core v6: PD=3 counted-vmcnt, 4 LDS buffers, ONE barrier per
// K-step. Iter kt: {wait vmcnt(2L) [tile kt landed]; s_barrier;
// STAGE(kt+3) -> buffer read at kt-1 (reads complete before any wave's
// barrier arrival -> race-free); ds_read; MFMA}. 2-way chunk swizzle both
// sides (0 conflicts, R6-verified). No setprio (m190: negative in lockstep).
// ---------------------------------------------------------------------------
template<int MW, int NW>
__device__ __forceinline__ void gemm_core_bf(
    const short* __restrict__ A, const short* __restrict__ BT,
    short* As, short* Bs, int m0, int n0, f32x4 acc[MW][NW]) {
  const int t = threadIdx.x;
  const int lane = t & 63, wid = t >> 6;
  const int wr = wid >> 1, wc = wid & 1;
  const int l15 = lane & 15, g = lane >> 4;
  constexpr int NT = 32;
  constexpr int LDT = MW / 2 + NW / 2;
  constexpr int ABUF = MW * 1024;
  constexpr int BBUF = NW * 1024;

#pragma unroll
  for (int m = 0; m < MW; m++)
#pragma unroll
    for (int n2 = 0; n2 < NW; n2++) acc[m][n2] = (f32x4){0.f, 0.f, 0.f, 0.f};

#define STAGE_(buf, kt)                                                        \
  {                                                                            \
    const int k0_ = (kt) * 32;                                                 \
    _Pragma("unroll")                                                          \
    for (int i_ = 0; i_ < NW / 2; i_++) {                                      \
      const int seg_ = i_ * 256 + t;                                           \
      const int row_ = seg_ >> 2, gl_ = seg_ & 3;                              \
      __builtin_amdgcn_global_load_lds(                                        \
          (gconst_t*)(BT + (size_t)(n0 + row_) * 1024 + k0_ +                  \
                      ((gl_ ^ ((row_ >> 1) & 3)) * 8)),                        \
          (lds_t*)(Bs + (buf) * BBUF + seg_ * 8), 16, 0, 0);                   \
    }                                                                          \
    _Pragma("unroll")                                                          \
    for (int i_ = 0; i_ < MW / 2; i_++) {                                      \
      const int seg_ = i_ * 256 + t;                                           \
      const int row_ = seg_ >> 2, gl_ = seg_ & 3;                              \
      __builtin_amdgcn_global_load_lds(                                        \
          (gconst_t*)(A + (size_t)(m0 + row_) * 1024 + k0_ +                   \
                      ((gl_ ^ ((row_ >> 1) & 3)) * 8)),                        \
          (lds_t*)(As + (buf) * ABUF + seg_ * 8), 16, 0, 0);                   \
    }                                                                          \
  }

  STAGE_(0, 0);
  STAGE_(1, 1);
  STAGE_(2, 2);
  int b0 = 0, b1 = 1, b2 = 2, b3 = 3;
  for (int kt = 0; kt < NT; ++kt) {
    // entry: tiles kt..min(kt+2,NT-1) outstanding; retire tile kt
    if (kt + 2 < NT) {
      wait_vm<2 * LDT>();
    } else if (kt + 2 == NT) {
      wait_vm<LDT>();
    } else {
      wait_vm<0>();
    }
    __builtin_amdgcn_sched_barrier(0);
    __builtin_amdgcn_s_barrier();   // tile kt visible to all waves; prev reads done
    __builtin_amdgcn_sched_barrier(0);
    if (kt + 3 < NT) STAGE_(b3, kt + 3);   // overwrites buffer read at kt-1

    const short* Ac = As + b0 * ABUF;
    const short* Bc = Bs + b0 * BBUF;
    bf16x8 a[MW], b[NW];
#pragma unroll
    for (int m = 0; m < MW; m++) {
      const int row = wr * (MW * 16) + m * 16 + l15;
      a[m] = *(const bf16x8*)(Ac + row * 32 + ((g ^ ((row >> 1) & 3)) * 8));
    }
#pragma unroll
    for (int n2 = 0; n2 < NW; n2++) {
      const int row = wc * (NW * 16) + n2 * 16 + l15;
      b[n2] = *(const bf16x8*)(Bc + row * 32 + ((g ^ ((row >> 1) & 3)) * 8));
    }
#pragma unroll
    for (int m = 0; m < MW; m++)
#pragma unroll
      for (int n2 = 0; n2 < NW; n2++)
        acc[m][n2] = __builtin_amdgcn_mfma_f32_16x16x32_bf16(a[m], b[n2], acc[m][n2], 0, 0, 0);
    const int tmp = b0; b0 = b1; b1 = b2; b2 = b3; b3 = tmp;
  }
#undef STAGE_
}

// Projections: 128x128 tiles, 1D grid 512, XCD-chunked. y==2 (V) writes its
// tile TRANSPOSED to VpT via an in-LDS transpose epilogue.
__global__ __launch_bounds__(256) void gemm_proj(
    const short* __restrict__ Abf, const short* __restrict__ WTb,
    short* __restrict__ Pb, short* __restrict__ VpT,
    const float* __restrict__ gb) {
  __shared__ short As[4 * 4096];
  __shared__ short Bs[4 * 4096];
  const int bid = blockIdx.x;
  const int xcd = bid & 7, ord = bid >> 3;
  const int y = xcd >> 1, nh = xcd & 1;
  const int m0 = (ord & 15) * 128;
  const int n0 = (nh * 4 + (ord >> 4)) * 128;
  const short* A = Abf + (size_t)((y <= 2) ? y : 2) * 2097152u;
  const short* BT = WTb + (size_t)y * (1024u * 1024u);
  f32x4 acc[4][4];
  gemm_core_bf<4, 4>(A, BT, As, Bs, m0, n0, acc);
  const int t = threadIdx.x, lane = t & 63, wid = t >> 6;
  const int wr = wid >> 1, wc = wid & 1, l15 = lane & 15, g = lane >> 4;

  if (y == 2) {
    short* Tr = As;
    __syncthreads();   // all LDS reads of the K-loop done before reuse
#pragma unroll
    for (int m = 0; m < 4; m++)
#pragma unroll
      for (int n2 = 0; n2 < 4; n2++)
#pragma unroll
        for (int j = 0; j < 4; j++) {
          const int r = wr * 64 + m * 16 + g * 4 + j;
          const int c = wc * 64 + n2 * 16 + l15;
          Tr[c * 128 + r] = cvt_bf16(acc[m][n2][j]);
        }
    __syncthreads();
    const int nz = (m0 >= 1024) ? 1 : 0;
    const int sbase = m0 & 1023;
#pragma unroll
    for (int p = 0; p < 8; p++) {
      const int unit = p * 256 + t;
      const int cl = unit >> 4, sr8 = unit & 15;
      const bf16x8 v = *(const bf16x8*)(Tr + cl * 128 + sr8 * 8);
      *(bf16x8*)(VpT + ((size_t)(nz * 1024 + n0 + cl)) * 1024 + sbase + sr8 * 8) = v;
    }
  } else {
    short* outp = Pb + (size_t)y * 2097152u;
#pragma unroll
    for (int m = 0; m < 4; m++)
#pragma unroll
      for (int n2 = 0; n2 < 4; n2++)
#pragma unroll
        for (int j = 0; j < 4; j++) {
          const int row = m0 + wr * 64 + m * 16 + g * 4 + j;
          const int col = n0 + wc * 64 + n2 * 16 + l15;
          float v = acc[m][n2][j];
          if (y == 3) { v += gb[col]; v = 1.0f / (1.0f + __expf(-v)); }
          outp[(size_t)row * 1024 + col] = cvt_bf16(v);
        }
  }
}

// Final projection: 64x64 tiles, 1D grid 512, XCD-chunked.
__global__ __launch_bounds__(256) void gemm_final(
    const short* __restrict__ Aobuf, const short* __restrict__ WTo,
    float* __restrict__ outp, const float* __restrict__ ob) {
  __shared__ short As[4 * 2048];
  __shared__ short Bs[4 * 2048];
  const int bid = blockIdx.x;
  const int xcd = bid & 7, ord = bid >> 3;
  const int mg = xcd >> 1, ng = xcd & 1;
  const int m0 = (mg * 8 + (ord & 7)) * 64;
  const int n0 = (ng * 8 + (ord >> 3)) * 64;
  f32x4 acc[2][2];
  gemm_core_bf<2, 2>(Aobuf, WTo, As, Bs, m0, n0, acc);
  const int t = threadIdx.x, lane = t & 63, wid = t >> 6;
  const int wr = wid >> 1, wc = wid & 1, l15 = lane & 15, g = lane >> 4;
#pragma unroll
  for (int m = 0; m < 2; m++)
#pragma unroll
    for (int n2 = 0; n2 < 2; n2++)
#pragma unroll
      for (int j = 0; j < 4; j++) {
        const int row = m0 + wr * 32 + m * 16 + g * 4 + j;
        const int col = n0 + wc * 32 + n2 * 16 + l15;
        outp[(size_t)row * 1024 + col] = acc[m][n2][j] + ob[col];
      }
}

// ---------------------------------------------------------------------------
// Flash attention KV-split (lns=1).
// ---------------------------------------------------------------------------
__global__ __launch_bounds__(256) void attn_split(
    const short* __restrict__ Qp, const short* __restrict__ Kp,
    const short* __restrict__ VpT, const short* __restrict__ biasP,
    float* __restrict__ mlbuf, short* __restrict__ OpartB, int lns) {
  __shared__ short Ks[64 * 64];
  __shared__ short Vt[64 * 64];
  __shared__ short Pl[4][16 * 64];

  const int t = threadIdx.x;
  const int lane = t & 63, w = t >> 6;
  const int l15 = lane & 15, g = lane >> 4;
  const int xb = blockIdx.x, h = blockIdx.y, n = blockIdx.z;
  const int sp = xb & ((1 << lns) - 1), qb = xb >> lns;
  const int itc = 16 >> lns;

  const int sbase = qb * 64 + w * 16;
  const short* qptr = Qp + (size_t)(n * S_ + sbase + l15) * HC_ + h * C_;
  const bf16x8 qf0 = *(const bf16x8*)(qptr + g * 8);
  const bf16x8 qf1 = *(const bf16x8*)(qptr + 32 + g * 8);

  float mrow[4], lsum[4];
  f32x4 oacc[4];
#pragma unroll
  for (int j = 0; j < 4; j++) { mrow[j] = -1e30f; lsum[j] = 0.f; }
#pragma unroll
  for (int cb = 0; cb < 4; cb++) oacc[cb] = (f32x4){0.f, 0.f, 0.f, 0.f};

  const int str = t >> 3, sc8 = (t & 7) * 8;
  const short* bbase = biasP + ((size_t)(n * 64 + qb * 4 + w) * 16 * 64 + lane) * 16;

  {
    const int t0 = sp * itc * 64;
    bf16x8 kA0 = *(const bf16x8*)(Kp + (size_t)(n * S_ + t0 + str) * HC_ + h * C_ + sc8);
    bf16x8 kA1 = *(const bf16x8*)(Kp + (size_t)(n * S_ + t0 + 32 + str) * HC_ + h * C_ + sc8);
    bf16x8 vA0 = *(const bf16x8*)(VpT + ((size_t)n * HC_ + h * C_ + str) * S_ + t0 + sc8);
    bf16x8 vA1 = *(const bf16x8*)(VpT + ((size_t)n * HC_ + h * C_ + 32 + str) * S_ + t0 + sc8);

    for (int it = 0; it < itc; ++it) {
      const int tg = sp * itc + it;
      __syncthreads();
      { const int kr = str;      *(bf16x8*)((char*)Ks + kr * 128 + ((sc8 * 2) ^ ((kr & 7) << 4))) = kA0; }
      { const int kr = 32 + str; *(bf16x8*)((char*)Ks + kr * 128 + ((sc8 * 2) ^ ((kr & 7) << 4))) = kA1; }
      { const int cr = str;      *(bf16x8*)((char*)Vt + cr * 128 + ((sc8 * 2) ^ ((cr & 7) << 4))) = vA0; }
      { const int cr = 32 + str; *(bf16x8*)((char*)Vt + cr * 128 + ((sc8 * 2) ^ ((cr & 7) << 4))) = vA1; }
      __syncthreads();

      const bf16x8 bf0 = *(const bf16x8*)(bbase + tg * 1024);
      const bf16x8 bf1 = *(const bf16x8*)(bbase + tg * 1024 + 8);
      const int t1 = ((it + 1 < itc) ? (tg + 1) : tg) * 64;
      bf16x8 kB0 = *(const bf16x8*)(Kp + (size_t)(n * S_ + t1 + str) * HC_ + h * C_ + sc8);
      bf16x8 kB1 = *(const bf16x8*)(Kp + (size_t)(n * S_ + t1 + 32 + str) * HC_ + h * C_ + sc8);
      bf16x8 vB0 = *(const bf16x8*)(VpT + ((size_t)n * HC_ + h * C_ + str) * S_ + t1 + sc8);
      bf16x8 vB1 = *(const bf16x8*)(VpT + ((size_t)n * HC_ + h * C_ + 32 + str) * S_ + t1 + sc8);

      f32x4 sacc[4];
#pragma unroll
      for (int nb = 0; nb < 4; nb++) sacc[nb] = (f32x4){0.f, 0.f, 0.f, 0.f};
      __builtin_amdgcn_s_setprio(1);
#pragma unroll
      for (int nb = 0; nb < 4; nb++) {
        const int krow = nb * 16 + l15;
        const bf16x8 b0 = *(const bf16x8*)((char*)Ks + krow * 128 + ((g * 16) ^ ((krow & 7) << 4)));
        const bf16x8 b1 = *(const bf16x8*)((char*)Ks + krow * 128 + ((64 + g * 16) ^ ((krow & 7) << 4)));
        sacc[nb] = __builtin_amdgcn_mfma_f32_16x16x32_bf16(qf0, b0, sacc[nb], 0, 0, 0);
        sacc[nb] = __builtin_amdgcn_mfma_f32_16x16x32_bf16(qf1, b1, sacc[nb], 0, 0, 0);
      }
      __builtin_amdgcn_s_setprio(0);

      float tmax[4];
#pragma unroll
      for (int j = 0; j < 4; j++) tmax[j] = -1e30f;
#pragma unroll
      for (int nb = 0; nb < 4; nb++)
#pragma unroll
        for (int j = 0; j < 4; j++) {
          const short bb = (nb < 2) ? bf0[nb * 4 + j] : bf1[(nb - 2) * 4 + j];
          const float lg = sacc[nb][j] * SC2 + bf2f(bb);
          sacc[nb][j] = lg;
          tmax[j] = fmaxf(tmax[j], lg);
        }
#pragma unroll
      for (int j = 0; j < 4; j++) {
#pragma unroll
        for (int d = 1; d < 16; d <<= 1)
          tmax[j] = fmaxf(tmax[j], __shfl_xor(tmax[j], d, 64));
        const float mn = fmaxf(mrow[j], tmax[j]);
        const float sc = exp2f(mrow[j] - mn);
        mrow[j] = mn;
        lsum[j] *= sc;
#pragma unroll
        for (int cb = 0; cb < 4; cb++) oacc[cb][j] *= sc;
        float ps = 0.f;
#pragma unroll
        for (int nb = 0; nb < 4; nb++) {
          const float p = exp2f(sacc[nb][j] - mn);
          sacc[nb][j] = p;
          ps += p;
        }
        lsum[j] += ps;
      }
      short* Pw = &Pl[w][0];
#pragma unroll
      for (int nb = 0; nb < 4; nb++)
#pragma unroll
        for (int j = 0; j < 4; j++) {
          const int pr = g * 4 + j;
          const int pcb = (nb * 16 + l15) * 2;
          *(short*)((char*)Pw + pr * 128 + (pcb ^ ((pr & 7) << 4))) = cvt_bf16(sacc[nb][j]);
        }
      __builtin_amdgcn_s_setprio(1);
#pragma unroll
      for (int kk = 0; kk < 2; kk++) {
        const bf16x8 pf = *(const bf16x8*)((char*)Pw + l15 * 128 + ((kk * 64 + g * 16) ^ ((l15 & 7) << 4)));
#pragma unroll
        for (int cb = 0; cb < 4; cb++) {
          const int vrow = cb * 16 + l15;
          const bf16x8 vf = *(const bf16x8*)((char*)Vt + vrow * 128 + ((kk * 64 + g * 16) ^ ((vrow & 7) << 4)));
          oacc[cb] = __builtin_amdgcn_mfma_f32_16x16x32_bf16(pf, vf, oacc[cb], 0, 0, 0);
        }
      }
      __builtin_amdgcn_s_setprio(0);
      kA0 = kB0; kA1 = kB1; vA0 = vB0; vA1 = vB1;
    }
  }
  const int slot = (((n * 16 + h) * 16 + qb) << lns) + sp;
  short* op = OpartB + (size_t)slot * 4096;
  float* mlp = mlbuf + (size_t)slot * 128;
#pragma unroll
  for (int j = 0; j < 4; j++) {
    float rs = lsum[j];
#pragma unroll
    for (int d = 1; d < 16; d <<= 1) rs += __shfl_xor(rs, d, 64);
    const int row = w * 16 + g * 4 + j;
#pragma unroll
    for (int cb = 0; cb < 4; cb++)
      op[row * 64 + cb * 16 + l15] = cvt_bf16(oacc[cb][j]);
    if (l15 == 0) { mlp[row * 2] = mrow[j]; mlp[row * 2 + 1] = rs; }
  }
}

// ---------------------------------------------------------------------------
__global__ __launch_bounds__(256) void attn_merge(
    const short* __restrict__ OpartB, const float* __restrict__ mlbuf,
    const short* __restrict__ Gp, short* __restrict__ ObufB, int lns) {
  const int qb = blockIdx.x, h = blockIdx.y, n = blockIdx.z;
  const int nsplit = 1 << lns;
  const int t = threadIdx.x;
  const int r = t >> 2, c0 = (t & 3) * 16;
  const int bslot = ((n * 16 + h) * 16 + qb) << lns;
  const float* mlb = mlbuf + (size_t)bslot * 128 + r * 2;

  float M = -1e30f;
  for (int sp = 0; sp < nsplit; sp++) M = fmaxf(M, mlb[(size_t)sp * 128]);
  float l = 0.f;
  for (int sp = 0; sp < nsplit; sp++)
    l += exp2f(mlb[(size_t)sp * 128] - M) * mlb[(size_t)sp * 128 + 1];
  const float inv = 1.0f / l;

  float acc[16];
#pragma unroll
  for (int k = 0; k < 16; k++) acc[k] = 0.f;
  for (int sp = 0; sp < nsplit; sp++) {
    const float wsc = exp2f(mlb[(size_t)sp * 128] - M);
    const short* op = OpartB + (size_t)(bslot + sp) * 4096 + r * 64 + c0;
    const bf16x8 v0 = *(const bf16x8*)(op);
    const bf16x8 v1 = *(const bf16x8*)(op + 8);
#pragma unroll
    for (int k = 0; k < 8; k++) {
      acc[k]     += wsc * bf2f(v0[k]);
      acc[8 + k] += wsc * bf2f(v1[k]);
    }
  }
  const int srow = qb * 64 + r;
  const size_t idx = (size_t)(n * S_ + srow) * HC_ + h * C_ + c0;
  const bf16x8 g0 = *(const bf16x8*)(Gp + idx);
  const bf16x8 g1 = *(const bf16x8*)(Gp + idx + 8);
  bf16x8 o0, o1;
#pragma unroll
  for (int k = 0; k < 8; k++) {
    o0[k] = cvt_bf16(acc[k] * inv * bf2f(g0[k]));
    o1[k] = cvt_bf16(acc[8 + k] * inv * bf2f(g1[k]));
  }
  *(bf16x8*)(ObufB + idx) = o0;
  *(bf16x8*)(ObufB + idx + 8) = o1;
}

// ---------------------------------------------------------------------------
extern "C" void kernel_launch(void* const* d_in, const int* in_sizes, int n_in,
                              void* d_out, int out_size, void* d_ws, size_t ws_size,
                              hipStream_t stream) {
  const float* Qin      = (const float*)d_in[0];
  const float* Kin      = (const float*)d_in[1];
  const float* Vin      = (const float*)d_in[2];
  const void*  seqMask  = d_in[3];
  const float* attMask  = (const float*)d_in[4];
  const float* QTrans   = (const float*)d_in[5];
  const float* KTrans   = (const float*)d_in[6];
  const float* VTrans   = (const float*)d_in[7];
  const float* GTrans_w = (const float*)d_in[8];
  const float* GTrans_b = (const float*)d_in[9];
  const float* out_w    = (const float*)d_in[10];
  const float* out_b    = (const float*)d_in[11];
  float* out = (float*)d_out;

  char* ws = (char*)d_ws;
  const size_t MB = 1048576u;
  short* WTb   = (short*)(ws);              // 10 MB: 5 transposed bf16 weights
  short* Abf   = (short*)(ws + 10 * MB);    // 12 MB: bf16 Qin,Kin,Vin
  short* Pb    = (short*)(ws + 22 * MB);    // 16 MB: Qp,Kp,(unused),Gp bf16
  short* VpT   = (short*)(ws + 38 * MB);    //  4 MB (written by gemm_proj y=2)
  short* ObufB = (short*)(ws + 42 * MB);    //  4 MB bf16 gated attn out
  short* biasP = (short*)(ws + 46 * MB);    //  4 MB pre-permuted bias
  const size_t partBase = 51 * MB;

  const short* Kp = Pb + (size_t)1u * 2097152u;
  const short* Gp = Pb + (size_t)3u * 2097152u;

  int lns = 0;
  for (int c = 1; c >= 0; c--) {
    const size_t slots = 512u << c;
    if (ws_size >= partBase + slots * (8192u + 512u)) { lns = c; break; }
  }
  const size_t slots = 512u << lns;
  short* OpartB = (short*)(ws + partBase);
  float* mlbuf  = (float*)(ws + partBase + slots * 8192u);

  hipLaunchKernelGGL(prep, dim3(10240), dim3(256), 0, stream,
                     QTrans, KTrans, VTrans, GTrans_w, out_w, WTb,
                     Qin, Kin, Vin, Abf,
                     attMask, (const unsigned char*)seqMask, biasP);
  hipLaunchKernelGGL(gemm_proj, dim3(512), dim3(256), 0, stream,
                     Abf, WTb, Pb, VpT, GTrans_b);
  hipLaunchKernelGGL(attn_split, dim3(16 << lns, 16, 2), dim3(256), 0, stream,
                     Pb, Kp, VpT, biasP, mlbuf, OpartB, lns);
  hipLaunchKernelGGL(attn_merge, dim3(16, 16, 2), dim3(256), 0, stream,
                     OpartB, mlbuf, Gp, ObufB, lns);
  hipLaunchKernelGGL(gemm_final, dim3(512), dim3(256), 0, stream,
                     ObufB, WTb + (size_t)4u * 1048576u, out, out_b);
}

// Round 20
// 102.928 us; speedup vs baseline: 1.1654x; 1.0900x over previous
//
#include <hip/hip_runtime.h>
#include <hip/hip_bf16.h>
#include <cstddef>

#define S_   1024
#define HC_  1024
#define C_   64
#define LOG2E 1.4426950408889634f
#define SC2   0.18033688011112042f   /* (1/8)*log2(e) */

typedef __attribute__((ext_vector_type(8))) short bf16x8;
typedef __attribute__((ext_vector_type(4))) short bf16x4;
typedef __attribute__((ext_vector_type(4))) float f32x4;

typedef __attribute__((address_space(1))) const void gconst_t;
typedef __attribute__((address_space(3))) void lds_t;

__device__ __forceinline__ short cvt_bf16(float f) {
  union { float f; unsigned u; } v; v.f = f;
  unsigned r = v.u + 0x7FFFu + ((v.u >> 16) & 1u);
  return (short)(r >> 16);
}
__device__ __forceinline__ float bf2f(short s) {
  union { float f; unsigned u; } v; v.u = ((unsigned)(unsigned short)s) << 16;
  return v.f;
}

// ---------------------------------------------------------------------------
// prep: weight transpose+cvt (blocks 0..5119), input cvt (5120..8191),
// bias pre-permute w/ inline mask-stride detect (8192..10239).
// ---------------------------------------------------------------------------
__global__ __launch_bounds__(256) void prep(
    const float* __restrict__ QT, const float* __restrict__ KT,
    const float* __restrict__ VT, const float* __restrict__ GW,
    const float* __restrict__ OW, short* __restrict__ WTb,
    const float* __restrict__ Qin, const float* __restrict__ Kin,
    const float* __restrict__ Vin, short* __restrict__ Abf,
    const float* __restrict__ att, const unsigned char* __restrict__ sm,
    short* __restrict__ biasP) {
  __shared__ short tile[32][33];
  __shared__ int a1, a4;
  const int bid = blockIdx.x;
  const int t = threadIdx.x;

  if (bid < 5120) {
    const int which = bid >> 10, xb = bid & 1023;
    const float* src = (which == 0) ? QT : (which == 1) ? KT : (which == 2) ? VT
                      : (which == 3) ? GW : OW;
    short* dst = WTb + (size_t)which * (1024u * 1024u);
    const int tj = (xb & 31) * 32;
    const int tk = (xb >> 5) * 32;
    const int r = t >> 3, c4 = (t & 7) * 4;
    const float4 v = *(const float4*)(src + (size_t)(tk + r) * 1024 + tj + c4);
    tile[c4 + 0][r] = cvt_bf16(v.x);
    tile[c4 + 1][r] = cvt_bf16(v.y);
    tile[c4 + 2][r] = cvt_bf16(v.z);
    tile[c4 + 3][r] = cvt_bf16(v.w);
    __syncthreads();
    bf16x4 o;
    o[0] = tile[r][c4 + 0]; o[1] = tile[r][c4 + 1];
    o[2] = tile[r][c4 + 2]; o[3] = tile[r][c4 + 3];
    *(bf16x4*)(dst + (size_t)(tj + r) * 1024 + tk + c4) = o;
  } else if (bid < 8192) {
    const int idx = bid - 5120;
    const int y = idx >> 10, xb = idx & 1023;
    const float* src = (y == 0) ? Qin : (y == 1) ? Kin : Vin;
    short* d = Abf + (size_t)y * 2097152u;
    const int i = (xb * 256 + t) * 8;
    const float4 a = *(const float4*)(src + i);
    const float4 b = *(const float4*)(src + i + 4);
    bf16x8 o;
    o[0] = cvt_bf16(a.x); o[1] = cvt_bf16(a.y); o[2] = cvt_bf16(a.z); o[3] = cvt_bf16(a.w);
    o[4] = cvt_bf16(b.x); o[5] = cvt_bf16(b.y); o[6] = cvt_bf16(b.z); o[7] = cvt_bf16(b.w);
    *(bf16x8*)(d + i) = o;
  } else {
    if (t == 0) { a1 = 0; a4 = 0; }
    __syncthreads();
    int l1 = 0, l4 = 0;
    for (int i = t; i < 2048; i += 256) {
      if (sm[i]) { if (i & 3) l1 = 1; else if (i & 4) l4 = 1; }
    }
    if (l1) atomicOr(&a1, 1);
    if (l4) atomicOr(&a4, 1);
    __syncthreads();
    const int mst = a1 ? 1 : (a4 ? 4 : 8);

    const int idx = bid - 8192;
    const int qw = idx & 63, tt = (idx >> 6) & 15, n = idx >> 10;
    const int lslot = t >> 2, i4 = t & 3;
    const int tc = tt * 64 + i4 * 16 + (lslot & 15);
    const int qbase = qw * 16 + ((lslot >> 4) << 2);
    const int smt = sm[(size_t)(n * 1024 + tc) * mst];
    bf16x4 o;
#pragma unroll
    for (int ii = 0; ii < 4; ii++) {
      const int q = qbase + ii;
      const int smq = sm[(size_t)(n * 1024 + q) * mst];
      const float val = (smq && smt) ? -1e4f : att[(size_t)q * 1024 + tc] * LOG2E;
      o[ii] = cvt_bf16(val);
    }
    short* dst = biasP + (((size_t)(n * 64 + qw) * 16 + tt) * 64 + lslot) * 16 + i4 * 4;
    *(bf16x4*)dst = o;
  }
}

// ---------------------------------------------------------------------------
// bf16 GEMM core (R5-proven, session-best proj: 40.4us): BK=64, dbuf LDS,
// global_load_lds staging with 8-chunk XOR swizzle (source chunk gl^(row&7),
// read chunk (kk*4+g)^(row&7); 0 bank conflicts, R5/R6-verified). 2-phase
// prefetch, ONE trailing __syncthreads per K-step, 16 K-steps.
// ---------------------------------------------------------------------------
template<int MW, int NW>
__device__ __forceinline__ void gemm_core_bf(
    const short* __restrict__ A, const short* __restrict__ BT,
    short* As, short* Bs, int m0, int n0, f32x4 acc[MW][NW]) {
  const int t = threadIdx.x;
  const int lane = t & 63, wid = t >> 6;
  const int wr = wid >> 1, wc = wid & 1;
  const int l15 = lane & 15, g = lane >> 4;
  constexpr int ABUF = MW * 2048;   // shorts per A buffer (MW*32 rows x 64)
  constexpr int BBUF = NW * 2048;

#pragma unroll
  for (int m = 0; m < MW; m++)
#pragma unroll
    for (int n2 = 0; n2 < NW; n2++) acc[m][n2] = (f32x4){0.f, 0.f, 0.f, 0.f};

#define STAGE_(buf, kt)                                                        \
  {                                                                            \
    const int k0_ = (kt) * 64;                                                 \
    _Pragma("unroll")                                                          \
    for (int i_ = 0; i_ < NW; i_++) {                                          \
      const int seg_ = i_ * 256 + t;                                           \
      const int row_ = seg_ >> 3, gl_ = seg_ & 7;                              \
      __builtin_amdgcn_global_load_lds(                                        \
          (gconst_t*)(BT + (size_t)(n0 + row_) * 1024 + k0_ +                  \
                      ((gl_ ^ (row_ & 7)) * 8)),                               \
          (lds_t*)(Bs + (buf) * BBUF + seg_ * 8), 16, 0, 0);                   \
    }                                                                          \
    _Pragma("unroll")                                                          \
    for (int i_ = 0; i_ < MW; i_++) {                                          \
      const int seg_ = i_ * 256 + t;                                           \
      const int row_ = seg_ >> 3, gl_ = seg_ & 7;                              \
      __builtin_amdgcn_global_load_lds(                                        \
          (gconst_t*)(A + (size_t)(m0 + row_) * 1024 + k0_ +                   \
                      ((gl_ ^ (row_ & 7)) * 8)),                               \
          (lds_t*)(As + (buf) * ABUF + seg_ * 8), 16, 0, 0);                   \
    }                                                                          \
  }

  STAGE_(0, 0);
  __syncthreads();
  int cur = 0;
  for (int kt = 0; kt < 16; ++kt) {
    if (kt + 1 < 16) STAGE_(cur ^ 1, kt + 1);
    const short* Ac = As + cur * ABUF;
    const short* Bc = Bs + cur * BBUF;
    bf16x8 a[MW][2], b[NW][2];
#pragma unroll
    for (int m = 0; m < MW; m++) {
      const int row = wr * (MW * 16) + m * 16 + l15;
#pragma unroll
      for (int kk = 0; kk < 2; kk++)
        a[m][kk] = *(const bf16x8*)(Ac + row * 64 + (((kk * 4 + g) ^ (row & 7)) * 8));
    }
#pragma unroll
    for (int n2 = 0; n2 < NW; n2++) {
      const int row = wc * (NW * 16) + n2 * 16 + l15;
#pragma unroll
      for (int kk = 0; kk < 2; kk++)
        b[n2][kk] = *(const bf16x8*)(Bc + row * 64 + (((kk * 4 + g) ^ (row & 7)) * 8));
    }
    __builtin_amdgcn_s_setprio(1);
#pragma unroll
    for (int kk = 0; kk < 2; kk++)
#pragma unroll
      for (int m = 0; m < MW; m++)
#pragma unroll
        for (int n2 = 0; n2 < NW; n2++)
          acc[m][n2] = __builtin_amdgcn_mfma_f32_16x16x32_bf16(a[m][kk], b[n2][kk], acc[m][n2], 0, 0, 0);
    __builtin_amdgcn_s_setprio(0);
    __syncthreads();   // drains vmcnt (next-tile loads landed) + LDS reads done
    cur ^= 1;
  }
#undef STAGE_
}

// Projections: 128x128 tiles, 1D grid 512, XCD-chunked (y = xcd>>1,
// n-half = xcd&1). y==2 (V) writes its tile TRANSPOSED to VpT via in-LDS
// transpose epilogue; row-major Vp never materialized.
__global__ __launch_bounds__(256) void gemm_proj(
    const short* __restrict__ Abf, const short* __restrict__ WTb,
    short* __restrict__ Pb, short* __restrict__ VpT,
    const float* __restrict__ gb) {
  __shared__ short As[2 * 8192];
  __shared__ short Bs[2 * 8192];
  const int bid = blockIdx.x;
  const int xcd = bid & 7, ord = bid >> 3;
  const int y = xcd >> 1, nh = xcd & 1;
  const int m0 = (ord & 15) * 128;
  const int n0 = (nh * 4 + (ord >> 4)) * 128;
  const short* A = Abf + (size_t)((y <= 2) ? y : 2) * 2097152u;
  const short* BT = WTb + (size_t)y * (1024u * 1024u);
  f32x4 acc[4][4];
  gemm_core_bf<4, 4>(A, BT, As, Bs, m0, n0, acc);
  const int t = threadIdx.x, lane = t & 63, wid = t >> 6;
  const int wr = wid >> 1, wc = wid & 1, l15 = lane & 15, g = lane >> 4;

  if (y == 2) {
    // K-loop's final __syncthreads already ran -> LDS reads complete; safe
    // to reuse As as the 128x128 transpose buffer.
    short* Tr = As;
#pragma unroll
    for (int m = 0; m < 4; m++)
#pragma unroll
      for (int n2 = 0; n2 < 4; n2++)
#pragma unroll
        for (int j = 0; j < 4; j++) {
          const int r = wr * 64 + m * 16 + g * 4 + j;
          const int c = wc * 64 + n2 * 16 + l15;
          Tr[c * 128 + r] = cvt_bf16(acc[m][n2][j]);
        }
    __syncthreads();
    const int nz = (m0 >= 1024) ? 1 : 0;
    const int sbase = m0 & 1023;
#pragma unroll
    for (int p = 0; p < 8; p++) {
      const int unit = p * 256 + t;
      const int cl = unit >> 4, sr8 = unit & 15;
      const bf16x8 v = *(const bf16x8*)(Tr + cl * 128 + sr8 * 8);
      *(bf16x8*)(VpT + ((size_t)(nz * 1024 + n0 + cl)) * 1024 + sbase + sr8 * 8) = v;
    }
  } else {
    short* outp = Pb + (size_t)y * 2097152u;
#pragma unroll
    for (int m = 0; m < 4; m++)
#pragma unroll
      for (int n2 = 0; n2 < 4; n2++)
#pragma unroll
        for (int j = 0; j < 4; j++) {
          const int row = m0 + wr * 64 + m * 16 + g * 4 + j;
          const int col = n0 + wc * 64 + n2 * 16 + l15;
          float v = acc[m][n2][j];
          if (y == 3) { v += gb[col]; v = 1.0f / (1.0f + __expf(-v)); }
          outp[(size_t)row * 1024 + col] = cvt_bf16(v);
        }
  }
}

// Final projection: 64x64 tiles, 1D grid 512, XCD-chunked; same R5 core.
__global__ __launch_bounds__(256) void gemm_final(
    const short* __restrict__ Aobuf, const short* __restrict__ WTo,
    float* __restrict__ outp, const float* __restrict__ ob) {
  __shared__ short As[2 * 4096];
  __shared__ short Bs[2 * 4096];
  const int bid = blockIdx.x;
  const int xcd = bid & 7, ord = bid >> 3;
  const int mg = xcd >> 1, ng = xcd & 1;
  const int m0 = (mg * 8 + (ord & 7)) * 64;
  const int n0 = (ng * 8 + (ord >> 3)) * 64;
  f32x4 acc[2][2];
  gemm_core_bf<2, 2>(Aobuf, WTo, As, Bs, m0, n0, acc);
  const int t = threadIdx.x, lane = t & 63, wid = t >> 6;
  const int wr = wid >> 1, wc = wid & 1, l15 = lane & 15, g = lane >> 4;
#pragma unroll
  for (int m = 0; m < 2; m++)
#pragma unroll
    for (int n2 = 0; n2 < 2; n2++)
#pragma unroll
      for (int j = 0; j < 4; j++) {
        const int row = m0 + wr * 32 + m * 16 + g * 4 + j;
        const int col = n0 + wc * 32 + n2 * 16 + l15;
        outp[(size_t)row * 1024 + col] = acc[m][n2][j] + ob[col];
      }
}

// ---------------------------------------------------------------------------
// Flash attention KV-split (lns=1).
// ---------------------------------------------------------------------------
__global__ __launch_bounds__(256) void attn_split(
    const short* __restrict__ Qp, const short* __restrict__ Kp,
    const short* __restrict__ VpT, const short* __restrict__ biasP,
    float* __restrict__ mlbuf, short* __restrict__ OpartB, int lns) {
  __shared__ short Ks[64 * 64];
  __shared__ short Vt[64 * 64];
  __shared__ short Pl[4][16 * 64];

  const int t = threadIdx.x;
  const int lane = t & 63, w = t >> 6;
  const int l15 = lane & 15, g = lane >> 4;
  const int xb = blockIdx.x, h = blockIdx.y, n = blockIdx.z;
  const int sp = xb & ((1 << lns) - 1), qb = xb >> lns;
  const int itc = 16 >> lns;

  const int sbase = qb * 64 + w * 16;
  const short* qptr = Qp + (size_t)(n * S_ + sbase + l15) * HC_ + h * C_;
  const bf16x8 qf0 = *(const bf16x8*)(qptr + g * 8);
  const bf16x8 qf1 = *(const bf16x8*)(qptr + 32 + g * 8);

  float mrow[4], lsum[4];
  f32x4 oacc[4];
#pragma unroll
  for (int j = 0; j < 4; j++) { mrow[j] = -1e30f; lsum[j] = 0.f; }
#pragma unroll
  for (int cb = 0; cb < 4; cb++) oacc[cb] = (f32x4){0.f, 0.f, 0.f, 0.f};

  const int str = t >> 3, sc8 = (t & 7) * 8;
  const short* bbase = biasP + ((size_t)(n * 64 + qb * 4 + w) * 16 * 64 + lane) * 16;

  {
    const int t0 = sp * itc * 64;
    bf16x8 kA0 = *(const bf16x8*)(Kp + (size_t)(n * S_ + t0 + str) * HC_ + h * C_ + sc8);
    bf16x8 kA1 = *(const bf16x8*)(Kp + (size_t)(n * S_ + t0 + 32 + str) * HC_ + h * C_ + sc8);
    bf16x8 vA0 = *(const bf16x8*)(VpT + ((size_t)n * HC_ + h * C_ + str) * S_ + t0 + sc8);
    bf16x8 vA1 = *(const bf16x8*)(VpT + ((size_t)n * HC_ + h * C_ + 32 + str) * S_ + t0 + sc8);

    for (int it = 0; it < itc; ++it) {
      const int tg = sp * itc + it;
      __syncthreads();
      { const int kr = str;      *(bf16x8*)((char*)Ks + kr * 128 + ((sc8 * 2) ^ ((kr & 7) << 4))) = kA0; }
      { const int kr = 32 + str; *(bf16x8*)((char*)Ks + kr * 128 + ((sc8 * 2) ^ ((kr & 7) << 4))) = kA1; }
      { const int cr = str;      *(bf16x8*)((char*)Vt + cr * 128 + ((sc8 * 2) ^ ((cr & 7) << 4))) = vA0; }
      { const int cr = 32 + str; *(bf16x8*)((char*)Vt + cr * 128 + ((sc8 * 2) ^ ((cr & 7) << 4))) = vA1; }
      __syncthreads();

      const bf16x8 bf0 = *(const bf16x8*)(bbase + tg * 1024);
      const bf16x8 bf1 = *(const bf16x8*)(bbase + tg * 1024 + 8);
      const int t1 = ((it + 1 < itc) ? (tg + 1) : tg) * 64;
      bf16x8 kB0 = *(const bf16x8*)(Kp + (size_t)(n * S_ + t1 + str) * HC_ + h * C_ + sc8);
      bf16x8 kB1 = *(const bf16x8*)(Kp + (size_t)(n * S_ + t1 + 32 + str) * HC_ + h * C_ + sc8);
      bf16x8 vB0 = *(const bf16x8*)(VpT + ((size_t)n * HC_ + h * C_ + str) * S_ + t1 + sc8);
      bf16x8 vB1 = *(const bf16x8*)(VpT + ((size_t)n * HC_ + h * C_ + 32 + str) * S_ + t1 + sc8);

      f32x4 sacc[4];
#pragma unroll
      for (int nb = 0; nb < 4; nb++) sacc[nb] = (f32x4){0.f, 0.f, 0.f, 0.f};
      __builtin_amdgcn_s_setprio(1);
#pragma unroll
      for (int nb = 0; nb < 4; nb++) {
        const int krow = nb * 16 + l15;
        const bf16x8 b0 = *(const bf16x8*)((char*)Ks + krow * 128 + ((g * 16) ^ ((krow & 7) << 4)));
        const bf16x8 b1 = *(const bf16x8*)((char*)Ks + krow * 128 + ((64 + g * 16) ^ ((krow & 7) << 4)));
        sacc[nb] = __builtin_amdgcn_mfma_f32_16x16x32_bf16(qf0, b0, sacc[nb], 0, 0, 0);
        sacc[nb] = __builtin_amdgcn_mfma_f32_16x16x32_bf16(qf1, b1, sacc[nb], 0, 0, 0);
      }
      __builtin_amdgcn_s_setprio(0);

      float tmax[4];
#pragma unroll
      for (int j = 0; j < 4; j++) tmax[j] = -1e30f;
#pragma unroll
      for (int nb = 0; nb < 4; nb++)
#pragma unroll
        for (int j = 0; j < 4; j++) {
          const short bb = (nb < 2) ? bf0[nb * 4 + j] : bf1[(nb - 2) * 4 + j];
          const float lg = sacc[nb][j] * SC2 + bf2f(bb);
          sacc[nb][j] = lg;
          tmax[j] = fmaxf(tmax[j], lg);
        }
#pragma unroll
      for (int j = 0; j < 4; j++) {
#pragma unroll
        for (int d = 1; d < 16; d <<= 1)
          tmax[j] = fmaxf(tmax[j], __shfl_xor(tmax[j], d, 64));
        const float mn = fmaxf(mrow[j], tmax[j]);
        const float sc = exp2f(mrow[j] - mn);
        mrow[j] = mn;
        lsum[j] *= sc;
#pragma unroll
        for (int cb = 0; cb < 4; cb++) oacc[cb][j] *= sc;
        float ps = 0.f;
#pragma unroll
        for (int nb = 0; nb < 4; nb++) {
          const float p = exp2f(sacc[nb][j] - mn);
          sacc[nb][j] = p;
          ps += p;
        }
        lsum[j] += ps;
      }
      short* Pw = &Pl[w][0];
#pragma unroll
      for (int nb = 0; nb < 4; nb++)
#pragma unroll
        for (int j = 0; j < 4; j++) {
          const int pr = g * 4 + j;
          const int pcb = (nb * 16 + l15) * 2;
          *(short*)((char*)Pw + pr * 128 + (pcb ^ ((pr & 7) << 4))) = cvt_bf16(sacc[nb][j]);
        }
      __builtin_amdgcn_s_setprio(1);
#pragma unroll
      for (int kk = 0; kk < 2; kk++) {
        const bf16x8 pf = *(const bf16x8*)((char*)Pw + l15 * 128 + ((kk * 64 + g * 16) ^ ((l15 & 7) << 4)));
#pragma unroll
        for (int cb = 0; cb < 4; cb++) {
          const int vrow = cb * 16 + l15;
          const bf16x8 vf = *(const bf16x8*)((char*)Vt + vrow * 128 + ((kk * 64 + g * 16) ^ ((vrow & 7) << 4)));
          oacc[cb] = __builtin_amdgcn_mfma_f32_16x16x32_bf16(pf, vf, oacc[cb], 0, 0, 0);
        }
      }
      __builtin_amdgcn_s_setprio(0);
      kA0 = kB0; kA1 = kB1; vA0 = vB0; vA1 = vB1;
    }
  }
  const int slot = (((n * 16 + h) * 16 + qb) << lns) + sp;
  short* op = OpartB + (size_t)slot * 4096;
  float* mlp = mlbuf + (size_t)slot * 128;
#pragma unroll
  for (int j = 0; j < 4; j++) {
    float rs = lsum[j];
#pragma unroll
    for (int d = 1; d < 16; d <<= 1) rs += __shfl_xor(rs, d, 64);
    const int row = w * 16 + g * 4 + j;
#pragma unroll
    for (int cb = 0; cb < 4; cb++)
      op[row * 64 + cb * 16 + l15] = cvt_bf16(oacc[cb][j]);
    if (l15 == 0) { mlp[row * 2] = mrow[j]; mlp[row * 2 + 1] = rs; }
  }
}

// ---------------------------------------------------------------------------
__global__ __launch_bounds__(256) void attn_merge(
    const short* __restrict__ OpartB, const float* __restrict__ mlbuf,
    const short* __restrict__ Gp, short* __restrict__ ObufB, int lns) {
  const int qb = blockIdx.x, h = blockIdx.y, n = blockIdx.z;
  const int nsplit = 1 << lns;
  const int t = threadIdx.x;
  const int r = t >> 2, c0 = (t & 3) * 16;
  const int bslot = ((n * 16 + h) * 16 + qb) << lns;
  const float* mlb = mlbuf + (size_t)bslot * 128 + r * 2;

  float M = -1e30f;
  for (int sp = 0; sp < nsplit; sp++) M = fmaxf(M, mlb[(size_t)sp * 128]);
  float l = 0.f;
  for (int sp = 0; sp < nsplit; sp++)
    l += exp2f(mlb[(size_t)sp * 128] - M) * mlb[(size_t)sp * 128 + 1];
  const float inv = 1.0f / l;

  float acc[16];
#pragma unroll
  for (int k = 0; k < 16; k++) acc[k] = 0.f;
  for (int sp = 0; sp < nsplit; sp++) {
    const float wsc = exp2f(mlb[(size_t)sp * 128] - M);
    const short* op = OpartB + (size_t)(bslot + sp) * 4096 + r * 64 + c0;
    const bf16x8 v0 = *(const bf16x8*)(op);
    const bf16x8 v1 = *(const bf16x8*)(op + 8);
#pragma unroll
    for (int k = 0; k < 8; k++) {
      acc[k]     += wsc * bf2f(v0[k]);
      acc[8 + k] += wsc * bf2f(v1[k]);
    }
  }
  const int srow = qb * 64 + r;
  const size_t idx = (size_t)(n * S_ + srow) * HC_ + h * C_ + c0;
  const bf16x8 g0 = *(const bf16x8*)(Gp + idx);
  const bf16x8 g1 = *(const bf16x8*)(Gp + idx + 8);
  bf16x8 o0, o1;
#pragma unroll
  for (int k = 0; k < 8; k++) {
    o0[k] = cvt_bf16(acc[k] * inv * bf2f(g0[k]));
    o1[k] = cvt_bf16(acc[8 + k] * inv * bf2f(g1[k]));
  }
  *(bf16x8*)(ObufB + idx) = o0;
  *(bf16x8*)(ObufB + idx + 8) = o1;
}

// ---------------------------------------------------------------------------
extern "C" void kernel_launch(void* const* d_in, const int* in_sizes, int n_in,
                              void* d_out, int out_size, void* d_ws, size_t ws_size,
                              hipStream_t stream) {
  const float* Qin      = (const float*)d_in[0];
  const float* Kin      = (const float*)d_in[1];
  const float* Vin      = (const float*)d_in[2];
  const void*  seqMask  = d_in[3];
  const float* attMask  = (const float*)d_in[4];
  const float* QTrans   = (const float*)d_in[5];
  const float* KTrans   = (const float*)d_in[6];
  const float* VTrans   = (const float*)d_in[7];
  const float* GTrans_w = (const float*)d_in[8];
  const float* GTrans_b = (const float*)d_in[9];
  const float* out_w    = (const float*)d_in[10];
  const float* out_b    = (const float*)d_in[11];
  float* out = (float*)d_out;

  char* ws = (char*)d_ws;
  const size_t MB = 1048576u;
  short* WTb   = (short*)(ws);              // 10 MB: 5 transposed bf16 weights
  short* Abf   = (short*)(ws + 10 * MB);    // 12 MB: bf16 Qin,Kin,Vin
  short* Pb    = (short*)(ws + 22 * MB);    // 16 MB: Qp,Kp,(unused),Gp bf16
  short* VpT   = (short*)(ws + 38 * MB);    //  4 MB (written by gemm_proj y=2)
  short* ObufB = (short*)(ws + 42 * MB);    //  4 MB bf16 gated attn out
  short* biasP = (short*)(ws + 46 * MB);    //  4 MB pre-permuted bias
  const size_t partBase = 51 * MB;

  const short* Kp = Pb + (size_t)1u * 2097152u;
  const short* Gp = Pb + (size_t)3u * 2097152u;

  int lns = 0;
  for (int c = 1; c >= 0; c--) {
    const size_t slots = 512u << c;
    if (ws_size >= partBase + slots * (8192u + 512u)) { lns = c; break; }
  }
  const size_t slots = 512u << lns;
  short* OpartB = (short*)(ws + partBase);
  float* mlbuf  = (float*)(ws + partBase + slots * 8192u);

  hipLaunchKernelGGL(prep, dim3(10240), dim3(256), 0, stream,
                     QTrans, KTrans, VTrans, GTrans_w, out_w, WTb,
                     Qin, Kin, Vin, Abf,
                     attMask, (const unsigned char*)seqMask, biasP);
  hipLaunchKernelGGL(gemm_proj, dim3(512), dim3(256), 0, stream,
                     Abf, WTb, Pb, VpT, GTrans_b);
  hipLaunchKernelGGL(attn_split, dim3(16 << lns, 16, 2), dim3(256), 0, stream,
                     Pb, Kp, VpT, biasP, mlbuf, OpartB, lns);
  hipLaunchKernelGGL(attn_merge, dim3(16, 16, 2), dim3(256), 0, stream,
                     OpartB, mlbuf, Gp, ObufB, lns);
  hipLaunchKernelGGL(gemm_final, dim3(512), dim3(256), 0, stream,
                     ObufB, WTb + (size_t)4u * 1048576u, out, out_b);
}